// Round 6
// baseline (242.530 us; speedup 1.0000x reference)
//
#include <hip/hip_runtime.h>

#define B 2
#define N0 16384
#define HW 16384
#define PADW 130
#define OUTC 256
#define M_ROWS 8192  // B*64*64
#define MAXP 32      // max points/cell tracked (lambda=1 Poisson; P(>32) ~ 0)

typedef short s16x8 __attribute__((ext_vector_type(8)));
typedef float f32x4 __attribute__((ext_vector_type(4)));

__device__ __forceinline__ unsigned short f2bf(float f) {
    union { float f; unsigned int u; } v; v.f = f;
    unsigned int u = v.u;
    return (unsigned short)((u + 0x7fffu + ((u >> 16) & 1u)) >> 16);
}
__device__ __forceinline__ float bf2f(unsigned short h) {
    union { unsigned int u; float f; } v; v.u = ((unsigned int)h) << 16;
    return v.f;
}

// async global->LDS, 16B per lane; LDS dest = wave-uniform base + lane*16
__device__ __forceinline__ void gl_lds16(const void* g, void* l) {
    __builtin_amdgcn_global_load_lds(
        (const __attribute__((address_space(1))) unsigned int*)g,
        (__attribute__((address_space(3))) unsigned int*)l, 16, 0, 0);
}

__device__ __forceinline__ void cell_of(const float* __restrict__ loc, int r, int& ix, int& iy) {
    float lx = loc[r * 2 + 0];
    float ly = loc[r * 2 + 1];
    lx = fminf(fmaxf(lx, -1.f), 1.f);
    ly = fminf(fmaxf(ly, -1.f), 1.f);
    ix = min(max((int)rintf(((lx + 1.f) * 0.5f) * 127.f), 0), 127);
    iy = min(max((int)rintf(((ly + 1.f) * 0.5f) * 127.f), 0), 127);
}

// Build per-cell token lists. One thread per point (131072 total).
__global__ void fill_k(const float* __restrict__ l0, const float* __restrict__ l1,
                       const float* __restrict__ l2, const float* __restrict__ l3,
                       const int* __restrict__ i0, const int* __restrict__ i1,
                       const int* __restrict__ i2, const int* __restrict__ i3,
                       int* __restrict__ cnt32, unsigned short* __restrict__ list) {
    int p = blockIdx.x * 256 + threadIdx.x;
    int j = p >> 15, r = p & 32767;
    const float* loc = j == 0 ? l0 : j == 1 ? l1 : j == 2 ? l2 : l3;
    const int* idx = j == 0 ? i0 : j == 1 ? i1 : j == 2 ? i2 : i3;
    int ix, iy;
    cell_of(loc, r, ix, iy);
    int cidx = (((j << 1) + (r >> 14)) << 14) + iy * 128 + ix;
    int pos = atomicAdd(&cnt32[cidx], 1);
    if (pos < MAXP) list[cidx * MAXP + pos] = (unsigned short)idx[r];
}

// Merged: gather-average per padded cell (blocks < 15844) + weight prep (rest).
__global__ void prep_k(const float* __restrict__ x0, const float* __restrict__ x1,
                       const float* __restrict__ x2, const float* __restrict__ x3,
                       const int* __restrict__ cnt32, const unsigned short* __restrict__ list,
                       unsigned short* __restrict__ mapB,
                       const float* __restrict__ w0, const float* __restrict__ w1,
                       const float* __restrict__ w2, const float* __restrict__ w3,
                       unsigned short* __restrict__ wt) {
    if (blockIdx.x >= 15844) {
        // ---- weight prep: [co][ci][3][3] fp32 -> bf16 [co][(kh*3+kw)*C + ci]
        int i = (blockIdx.x - 15844) * 256 + threadIdx.x;
        if (i >= 2211840) return;
        int j, local;
        if (i < 147456) { j = 0; local = i; }
        else if (i < 442368) { j = 1; local = i - 147456; }
        else if (i < 1032192) { j = 2; local = i - 442368; }
        else { j = 3; local = i - 1032192; }
        const float* w = j == 0 ? w0 : j == 1 ? w1 : j == 2 ? w2 : w3;
        int lc = 6 + j, C = 1 << lc;
        int ci = local & (C - 1);
        int rest = local >> lc;  // co*9 + seg
        int seg = rest % 9, co = rest / 9;
        int kh = seg / 3, kw = seg % 3;
        wt[(size_t)2304 * (C - 64) + local] = f2bf(w[(((co * C) + ci) * 3 + kh) * 3 + kw]);
        return;
    }
    // ---- gather: wave-sliced cells, lanes_per_cell = C/8, 8 channels/lane (16B store)
    int W = (blockIdx.x * 256 + threadIdx.x) >> 6;  // global wave id
    if (W >= 63375) return;
    int lane = threadIdx.x & 63;
    int j, base;
    if (W < 4225) { j = 0; base = 0; }
    else if (W < 12675) { j = 1; base = 4225; }
    else if (W < 29575) { j = 2; base = 12675; }
    else { j = 3; base = 29575; }
    const float* x = j == 0 ? x0 : j == 1 ? x1 : j == 2 ? x2 : x3;
    const int C = 64 << j;
    const int ntok = 16384 >> (2 * j);
    int u = W - base;
    int cellLocal = (u << (3 - j)) + (lane >> (3 + j));  // < 33800
    int sub = lane & ((8 << j) - 1);
    int ch0 = sub * 8;
    int b = cellLocal / 16900;
    int cc = cellLocal - b * 16900;
    int py = cc / 130, px = cc - py * 130;
    unsigned short* dst = mapB + (size_t)33800 * (C - 64) + ((size_t)cellLocal * C) + ch0;
    float a0 = 0.f, a1 = 0.f, a2 = 0.f, a3 = 0.f, a4 = 0.f, a5 = 0.f, a6 = 0.f, a7 = 0.f;
    if (py >= 1 && py <= 128 && px >= 1 && px <= 128) {
        int cidx = (((j << 1) + b) << 14) + (py - 1) * 128 + (px - 1);
        int n = cnt32[cidx];
        float inv = 1.0f / ((float)n + 1e-6f);
        int nn = min(n, MAXP);
        const unsigned short* lst = list + (size_t)cidx * MAXP;
        for (int p = 0; p < nn; p++) {
            int tok = lst[p];
            const float* xr = x + ((size_t)b * ntok + tok) * C + ch0;
            float4 v0 = *(const float4*)xr;
            float4 v1 = *(const float4*)(xr + 4);
            a0 += v0.x; a1 += v0.y; a2 += v0.z; a3 += v0.w;
            a4 += v1.x; a5 += v1.y; a6 += v1.z; a7 += v1.w;
        }
        a0 *= inv; a1 *= inv; a2 *= inv; a3 *= inv;
        a4 *= inv; a5 *= inv; a6 *= inv; a7 *= inv;
    }
    uint4 o;
    o.x = (unsigned int)f2bf(a0) | ((unsigned int)f2bf(a1) << 16);
    o.y = (unsigned int)f2bf(a2) | ((unsigned int)f2bf(a3) << 16);
    o.z = (unsigned int)f2bf(a4) | ((unsigned int)f2bf(a5) << 16);
    o.w = (unsigned int)f2bf(a6) | ((unsigned int)f2bf(a7) << 16);
    *(uint4*)dst = o;
}

// Split-K implicit-GEMM conv, double-buffered LDS. 2 waves/block, wave tile 128x64
// (8x4 16x16x32 frags -> 2.67 MFMA per ds_read_b128 vs 2.0 for 64x64 tiles).
// 8 chunk-slots (z): j={3,3,3,3,2,2,1,0}; block tile 128x128; slot z writes P[z].
__global__ __launch_bounds__(128) void conv_mfma(const unsigned short* __restrict__ mapB,
                                                 const unsigned short* __restrict__ wt,
                                                 unsigned short* __restrict__ P) {
    __shared__ unsigned short As[2][128][32];  // 16 KB
    __shared__ unsigned short Bs[2][128][32];  // 16 KB
    const int t = threadIdx.x;
    const int lane = t & 63;
    const int w = t >> 6;  // 0..1 : wave covers cols w*64..+64, all 128 rows
    const int z = blockIdx.z;
    const int j = (z < 4) ? 3 : (z < 6) ? 2 : (z == 6) ? 1 : 0;
    const int lc = 6 + j;
    const int C = 1 << lc;
    const int K = 9 * C;
    const int s0 = (z < 4) ? z * 36 : (z == 5 ? 36 : 0);
    const int s1 = s0 + (j == 0 ? 18 : 36);
    const unsigned short* mapBj = mapB + (size_t)33800 * (C - 64);
    const unsigned short* wtj = wt + (size_t)2304 * (C - 64);
    unsigned short* Pz = P + (size_t)z * M_ROWS * OUTC;
    const int mt = blockIdx.x, nt = blockIdx.y;

    // staging: lane -> (row lr, 16B quarter lq); each wave stages 4 A-rows-of-16 + 4 B
    const int lr = lane >> 2, lq = lane & 3;
    const unsigned short* pA[4];
    const unsigned short* pB[4];
#pragma unroll
    for (int i = 0; i < 4; i++) {
        int r = w * 64 + i * 16 + lr;
        int s = mt * 128 + r;
        int b = s >> 12, rem = s & 4095, oh = rem >> 6, ow = rem & 63;
        pA[i] = mapBj + (size_t)((b * PADW + 2 * oh) * PADW + 2 * ow) * C + lq * 8;
        pB[i] = wtj + (size_t)(nt * 128 + r) * K + lq * 8;
    }

    // incremental K-offsets: k = s*32
    int k0 = s0 << 5;
    int seg0 = k0 >> lc;
    int ci0 = k0 & (C - 1);
    int kh = seg0 / 3, kw = seg0 - 3 * kh;
    int offA = (kh * PADW + kw) * C + ci0;
    int offB = k0;

#pragma unroll
    for (int i = 0; i < 4; i++) {
        gl_lds16(pA[i] + offA, &As[0][w * 64 + i * 16][0]);
        gl_lds16(pB[i] + offB, &Bs[0][w * 64 + i * 16][0]);
    }

    f32x4 acc[8][4];
#pragma unroll
    for (int mi = 0; mi < 8; mi++)
#pragma unroll
        for (int ni = 0; ni < 4; ni++) acc[mi][ni] = (f32x4){0.f, 0.f, 0.f, 0.f};

    const int r16 = lane & 15, kg = lane >> 4;
    int buf = 0;
    for (int s = s0; s < s1; s++) {
        // advance offsets to step s+1
        ci0 += 32; offA += 32; offB += 32;
        if (ci0 == C) {
            ci0 = 0; kw++;
            if (kw == 3) { kw = 0; offA += (PADW - 3) * C; }
        }
        __syncthreads();  // drains prior prefetch (issued a full phase ago)
        if (s + 1 < s1) {
            int nb = buf ^ 1;
#pragma unroll
            for (int i = 0; i < 4; i++) {
                gl_lds16(pA[i] + offA, &As[nb][w * 64 + i * 16][0]);
                gl_lds16(pB[i] + offB, &Bs[nb][w * 64 + i * 16][0]);
            }
        }
        s16x8 a[8], b[4];
#pragma unroll
        for (int mi = 0; mi < 8; mi++) a[mi] = *(const s16x8*)&As[buf][mi * 16 + r16][kg * 8];
#pragma unroll
        for (int ni = 0; ni < 4; ni++)
            b[ni] = *(const s16x8*)&Bs[buf][w * 64 + ni * 16 + r16][kg * 8];
#pragma unroll
        for (int mi = 0; mi < 8; mi++)
#pragma unroll
            for (int ni = 0; ni < 4; ni++)
                acc[mi][ni] = __builtin_amdgcn_mfma_f32_16x16x32_bf16(a[mi], b[ni],
                                                                      acc[mi][ni], 0, 0, 0);
        buf ^= 1;
    }

    // C/D layout: col = lane&15, row = (lane>>4)*4 + reg
    const int rg = lane >> 4, c16 = lane & 15;
#pragma unroll
    for (int mi = 0; mi < 8; mi++)
#pragma unroll
        for (int ni = 0; ni < 4; ni++)
#pragma unroll
            for (int reg = 0; reg < 4; reg++) {
                int row = mt * 128 + mi * 16 + rg * 4 + reg;
                int col = nt * 128 + w * 64 + ni * 16 + c16;
                Pz[(size_t)row * OUTC + col] = f2bf(acc[mi][ni][reg]);
            }
}

// Sum the 8 slots into per-branch bf16 maps + channel stats (sum/sumsq of COMBINED v).
// Block bi covers rows bi*64..+64; thread t: 8 channels (cg*8), row-thread rt.
__global__ void combine_k(const unsigned short* __restrict__ P,
                          unsigned short* __restrict__ ybr, float* __restrict__ branchAcc) {
    __shared__ float red_s[8][256], red_ss[8][256];  // 16 KB
    int bi = blockIdx.x;  // 128
    int t = threadIdx.x;
    int cg = t & 31, rt = t >> 5;
    float s[4][8], ss[4][8];
#pragma unroll
    for (int j = 0; j < 4; j++)
#pragma unroll
        for (int k = 0; k < 8; k++) { s[j][k] = 0.f; ss[j][k] = 0.f; }
    for (int r = rt; r < 64; r += 8) {
        size_t row = (size_t)bi * 64 + r;
        const unsigned short* p = P + row * OUTC + cg * 8;
        float v[4][8];
#pragma unroll
        for (int j = 0; j < 4; j++)
#pragma unroll
            for (int k = 0; k < 8; k++) v[j][k] = 0.f;
#pragma unroll
        for (int z = 0; z < 8; z++) {
            int j = (z < 4) ? 3 : (z < 6) ? 2 : (z == 6) ? 1 : 0;
            uint4 u = *(const uint4*)(p + (size_t)z * M_ROWS * OUTC);
            v[j][0] += bf2f((unsigned short)(u.x & 0xffff));
            v[j][1] += bf2f((unsigned short)(u.x >> 16));
            v[j][2] += bf2f((unsigned short)(u.y & 0xffff));
            v[j][3] += bf2f((unsigned short)(u.y >> 16));
            v[j][4] += bf2f((unsigned short)(u.z & 0xffff));
            v[j][5] += bf2f((unsigned short)(u.z >> 16));
            v[j][6] += bf2f((unsigned short)(u.w & 0xffff));
            v[j][7] += bf2f((unsigned short)(u.w >> 16));
        }
#pragma unroll
        for (int j = 0; j < 4; j++) {
            uint4 o;
            o.x = (unsigned int)f2bf(v[j][0]) | ((unsigned int)f2bf(v[j][1]) << 16);
            o.y = (unsigned int)f2bf(v[j][2]) | ((unsigned int)f2bf(v[j][3]) << 16);
            o.z = (unsigned int)f2bf(v[j][4]) | ((unsigned int)f2bf(v[j][5]) << 16);
            o.w = (unsigned int)f2bf(v[j][6]) | ((unsigned int)f2bf(v[j][7]) << 16);
            *(uint4*)(ybr + ((size_t)j * M_ROWS + row) * OUTC + cg * 8) = o;
#pragma unroll
            for (int k = 0; k < 8; k++) {
                s[j][k] += v[j][k];
                ss[j][k] += v[j][k] * v[j][k];
            }
        }
    }
    for (int j = 0; j < 4; j++) {
#pragma unroll
        for (int k = 0; k < 8; k++) {
            red_s[rt][cg * 8 + k] = s[j][k];
            red_ss[rt][cg * 8 + k] = ss[j][k];
        }
        __syncthreads();
        float S = 0.f, SS = 0.f;
#pragma unroll
        for (int r = 0; r < 8; r++) { S += red_s[r][t]; SS += red_ss[r][t]; }
        atomicAdd(&branchAcc[j * 512 + t], S);
        atomicAdd(&branchAcc[j * 512 + 256 + t], SS);
        __syncthreads();
    }
}

// finalize: fold gamma/beta into per-branch scale/shift
__global__ void stats2_k(const float* __restrict__ branchAcc,
                         const float* __restrict__ g0, const float* __restrict__ g1,
                         const float* __restrict__ g2, const float* __restrict__ g3,
                         const float* __restrict__ b0, const float* __restrict__ b1,
                         const float* __restrict__ b2, const float* __restrict__ b3,
                         float* __restrict__ ssb) {
    int j = blockIdx.x, c = threadIdx.x;
    const float* gamma = j == 0 ? g0 : j == 1 ? g1 : j == 2 ? g2 : g3;
    const float* beta = j == 0 ? b0 : j == 1 ? b1 : j == 2 ? b2 : b3;
    float s = branchAcc[j * 512 + c];
    float ss = branchAcc[j * 512 + 256 + c];
    float mean = s * (1.f / 8192.f);
    float var = ss * (1.f / 8192.f) - mean * mean;
    float rs = rsqrtf(var + 1e-5f);
    float sc = gamma[c] * rs;
    ssb[j * 512 + c] = sc;
    ssb[j * 512 + OUTC + c] = beta[c] - mean * sc;
}

// fused: affine + 4-branch sum + NHWC->NCHW transpose; 8B loads, float4 stores
__global__ void out_k(const unsigned short* __restrict__ ybr, const float* __restrict__ ssb,
                      float* __restrict__ out) {
    __shared__ float tile[64][132];
    int oh = blockIdx.x, ct = blockIdx.y, b = blockIdx.z;  // 64, 2, 2
    int t = threadIdx.x;
    int cg = t & 31, rt = t >> 5;  // 4 channels each, 8 row-threads
    int c0 = ct * 128 + cg * 4;
    float sc[4][4], sh[4];
#pragma unroll
    for (int k = 0; k < 4; k++) {
        float shk = 0.f;
#pragma unroll
        for (int jj = 0; jj < 4; jj++) {
            sc[jj][k] = ssb[jj * 512 + c0 + k];
            shk += ssb[jj * 512 + OUTC + c0 + k];
        }
        sh[k] = shk;
    }
#pragma unroll
    for (int it = 0; it < 8; it++) {
        int ow = rt * 8 + it;
        size_t row = (size_t)b * 4096 + oh * 64 + ow;
        const unsigned short* p = ybr + row * OUTC + c0;
        float acc[4];
#pragma unroll
        for (int k = 0; k < 4; k++) acc[k] = sh[k];
#pragma unroll
        for (int jj = 0; jj < 4; jj++) {
            ushort4 u = *(const ushort4*)(p + (size_t)jj * M_ROWS * OUTC);
            acc[0] += bf2f(u.x) * sc[jj][0];
            acc[1] += bf2f(u.y) * sc[jj][1];
            acc[2] += bf2f(u.z) * sc[jj][2];
            acc[3] += bf2f(u.w) * sc[jj][3];
        }
#pragma unroll
        for (int k = 0; k < 4; k++) tile[ow][cg * 4 + k] = acc[k];
    }
    __syncthreads();
    int owq = t & 15, cp = t >> 4;
#pragma unroll
    for (int pass = 0; pass < 8; pass++) {
        int c = pass * 16 + cp;
        float4 v;
        v.x = tile[owq * 4 + 0][c];
        v.y = tile[owq * 4 + 1][c];
        v.z = tile[owq * 4 + 2][c];
        v.w = tile[owq * 4 + 3][c];
        *(float4*)(out + (((size_t)b * OUTC + ct * 128 + c) * 64 + oh) * 64 + owq * 4) = v;
    }
}

extern "C" void kernel_launch(void* const* d_in, const int* in_sizes, int n_in,
                              void* d_out, int out_size, void* d_ws, size_t ws_size,
                              hipStream_t stream) {
    char* ws = (char*)d_ws;
    size_t off = 0;
    auto alloc = [&](size_t bytes) {
        void* p = ws + off;
        off = (off + bytes + 255) & ~(size_t)255;
        return p;
    };
    unsigned short* P = (unsigned short*)alloc((size_t)8 * M_ROWS * OUTC * 2);   // 33.6 MB
    unsigned short* wt = (unsigned short*)alloc((size_t)2304 * 960 * 2);         // 4.4 MB
    unsigned short* mapB = (unsigned short*)alloc((size_t)33800 * 960 * 2);      // 64.9 MB
    unsigned short* ybr = mapB;  // dead after conv; 16.8 MB alias
    int* cnt32 = (int*)alloc((size_t)4 * 2 * HW * 4);                            // 0.5 MB
    float* branchAcc = (float*)alloc((size_t)4 * 512 * 4);                       // contiguous w/ cnt32
    unsigned short* list = (unsigned short*)alloc((size_t)4 * 2 * HW * MAXP * 2);// 8 MB
    float* ssb = (float*)alloc((size_t)4 * 512 * 4);

    hipMemsetAsync(cnt32, 0, (size_t)4 * 2 * HW * 4 + 4 * 512 * 4, stream);  // cnt32 + branchAcc

    fill_k<<<512, 256, 0, stream>>>(
        (const float*)d_in[1], (const float*)d_in[7], (const float*)d_in[13],
        (const float*)d_in[19],
        (const int*)d_in[2], (const int*)d_in[8], (const int*)d_in[14],
        (const int*)d_in[20], cnt32, list);
    prep_k<<<15844 + 8640, 256, 0, stream>>>(
        (const float*)d_in[0], (const float*)d_in[6], (const float*)d_in[12],
        (const float*)d_in[18], cnt32, list, mapB,
        (const float*)d_in[3], (const float*)d_in[9], (const float*)d_in[15],
        (const float*)d_in[21], wt);
    conv_mfma<<<dim3(64, 2, 8), 128, 0, stream>>>(mapB, wt, P);
    combine_k<<<128, 256, 0, stream>>>(P, ybr, branchAcc);
    stats2_k<<<4, 256, 0, stream>>>(branchAcc,
        (const float*)d_in[4], (const float*)d_in[10], (const float*)d_in[16],
        (const float*)d_in[22],
        (const float*)d_in[5], (const float*)d_in[11], (const float*)d_in[17],
        (const float*)d_in[23], ssb);
    out_k<<<dim3(64, 2, 2), 256, 0, stream>>>(ybr, ssb, (float*)d_out);
}